// Round 5
// baseline (96.721 us; speedup 1.0000x reference)
//
#include <hip/hip_runtime.h>
#include <hip/hip_bf16.h>
#include <stdint.h>

// Problem constants
#define S_LEN   4096
#define HIDDEN  1024
#define NHEAD   16
#define NKV     4
#define HD      64
#define WINDOW  512
#define L2E     1.4426950408889634f
#define QSCALE  (0.125f * L2E)

using short8 = __attribute__((ext_vector_type(8))) short;
using f32x4  = __attribute__((ext_vector_type(4))) float;
using f32x16 = __attribute__((ext_vector_type(16))) float;

// fp32 -> bf16, round-to-nearest-even
__device__ __forceinline__ uint16_t f2bf(float f) {
  uint32_t u = __builtin_bit_cast(uint32_t, f);
  u += 0x7fffu + ((u >> 16) & 1u);
  return (uint16_t)(u >> 16);
}
// round-to-nearest (ties up) — P values only (all >=0, bias ~2^-17)
__device__ __forceinline__ uint16_t f2bf_rn(float f) {
  uint32_t u = __builtin_bit_cast(uint32_t, f);
  return (uint16_t)((u + 0x8000u) >> 16);
}
__device__ __forceinline__ uint32_t pk2(float a, float b) {
  return (uint32_t)f2bf_rn(a) | ((uint32_t)f2bf_rn(b) << 16);
}

// async global->LDS, 16B per lane. LDS dest must be wave-uniform base + lane*16.
__device__ __forceinline__ void gld_lds16(void* lds, const void* g) {
  __builtin_amdgcn_global_load_lds(
      (const __attribute__((address_space(1))) char*)g,
      (__attribute__((address_space(3))) char*)lds, 16, 0, 0);
}

// ---------------------------------------------------------------------------
// Kernel 1: pack x, wq|wk|wv (concat rows), wo to bf16
// ---------------------------------------------------------------------------
__global__ __launch_bounds__(256) void k_tobf16(
    const float* __restrict__ x, const float* __restrict__ wq,
    const float* __restrict__ wk, const float* __restrict__ wv,
    const float* __restrict__ wo,
    uint16_t* __restrict__ xb, uint16_t* __restrict__ wqkvb,
    uint16_t* __restrict__ wob) {
  int i = blockIdx.x * 256 + threadIdx.x;  // one float4 per thread, exact grid
  const float4* src; uint16_t* dst; int off;
  if (i < 1048576)      { src = (const float4*)x;  dst = xb;                off = i; }
  else if (i < 1310720) { src = (const float4*)wq; dst = wqkvb;             off = i - 1048576; }
  else if (i < 1376256) { src = (const float4*)wk; dst = wqkvb + 1024*1024; off = i - 1310720; }
  else if (i < 1441792) { src = (const float4*)wv; dst = wqkvb + 1280*1024; off = i - 1376256; }
  else                  { src = (const float4*)wo; dst = wob;               off = i - 1441792; }
  float4 v = src[off];
  ushort4 o = { f2bf(v.x), f2bf(v.y), f2bf(v.z), f2bf(v.w) };
  *(ushort4*)(dst + (size_t)off * 4) = o;
}

// ---------------------------------------------------------------------------
// Kernel 2: QKV GEMM with fused RMSNorm + RoPE + cast + layout epilogue.
// BM=64, BN=128, BK=64; 4 waves in 2x2, wave tile 32x64 (acc[2][4]).
// Grid (64, 12) = 768 blocks = exactly 3 blocks/CU.
// ---------------------------------------------------------------------------
__global__ __launch_bounds__(256) void k_gemm_qkv(
    const uint16_t* __restrict__ A, const uint16_t* __restrict__ B,
    const float* __restrict__ cosb, const float* __restrict__ sinb,
    const float* __restrict__ qw, const float* __restrict__ kw,
    uint16_t* __restrict__ qout, uint16_t* __restrict__ kout,
    uint16_t* __restrict__ vtout) {
  __shared__ uint16_t As[64 * 64];
  __shared__ uint16_t Bs[128 * 64];
  const int K = 1024;
  const int t = threadIdx.x;
  const int lane = t & 63, w = t >> 6;
  const int wr = w >> 1, wc = w & 1;
  const int l16 = lane & 15, lg = lane >> 4;
  const int bm = blockIdx.x, bn = blockIdx.y;
  const uint16_t* Ab = A + (size_t)bm * 64 * K;
  const uint16_t* Bb = B + (size_t)bn * 128 * K;
  f32x4 acc[2][4] = {};
  for (int k0 = 0; k0 < K; k0 += 64) {
    __syncthreads();
    {  // stage A: 64x64 = 512 16B-chunks -> 2/thread
      int row = t >> 3, c8 = (t & 7) << 3;
      gld_lds16(&As[t * 8], Ab + (size_t)row * K + k0 + c8);
      int t2 = t + 256, row2 = t2 >> 3, c82 = (t2 & 7) << 3;
      gld_lds16(&As[t2 * 8], Ab + (size_t)row2 * K + k0 + c82);
    }
#pragma unroll
    for (int it = 0; it < 4; ++it) {  // stage B: 128x64 -> 4/thread
      int idx = it * 256 + t;
      int row = idx >> 3, c8 = (idx & 7) << 3;
      gld_lds16(&Bs[idx * 8], Bb + (size_t)row * K + k0 + c8);
    }
    __syncthreads();
#pragma unroll
    for (int kk = 0; kk < 2; ++kk) {
      short8 af[2], bq[4];
#pragma unroll
      for (int i = 0; i < 2; ++i)
        af[i] = *(const short8*)&As[(wr * 32 + i * 16 + l16) * 64 + kk * 32 + lg * 8];
#pragma unroll
      for (int j = 0; j < 4; ++j)
        bq[j] = *(const short8*)&Bs[(wc * 64 + j * 16 + l16) * 64 + kk * 32 + lg * 8];
#pragma unroll
      for (int i = 0; i < 2; ++i)
#pragma unroll
        for (int j = 0; j < 4; ++j)
          acc[i][j] = __builtin_amdgcn_mfma_f32_16x16x32_bf16(af[i], bq[j], acc[i][j], 0, 0, 0);
    }
  }

  // ---- fused epilogue ----
  const int hg = bn * 2 + wc;   // global 64-wide head slot, uniform per wave
  if (hg >= 20) {               // V: cast + transposed store
    const int kvh = hg - 20;
#pragma unroll
    for (int i = 0; i < 2; ++i) {
      int row0 = bm * 64 + wr * 32 + i * 16 + lg * 4;
#pragma unroll
      for (int j = 0; j < 4; ++j) {
        int d = j * 16 + l16;
        ushort4 o = { f2bf(acc[i][j][0]), f2bf(acc[i][j][1]),
                      f2bf(acc[i][j][2]), f2bf(acc[i][j][3]) };
        *(ushort4*)(vtout + (size_t)(kvh * 64 + d) * S_LEN + row0) = o;
      }
    }
    return;
  }
  // Q/K: RMSNorm + RoPE
  const float* nw = (hg < 16) ? qw : kw;
  float wgt[4];
#pragma unroll
  for (int j = 0; j < 4; ++j) wgt[j] = nw[j * 16 + l16];
#pragma unroll
  for (int i = 0; i < 2; ++i) {
    int row0 = bm * 64 + wr * 32 + i * 16 + lg * 4;
    float qn[4][4];
#pragma unroll
    for (int r = 0; r < 4; ++r) {
      float ss = acc[i][0][r] * acc[i][0][r] + acc[i][1][r] * acc[i][1][r]
               + acc[i][2][r] * acc[i][2][r] + acc[i][3][r] * acc[i][3][r];
      ss += __shfl_xor(ss, 1);
      ss += __shfl_xor(ss, 2);
      ss += __shfl_xor(ss, 4);
      ss += __shfl_xor(ss, 8);
      float inv = rsqrtf(ss * (1.0f / 64.0f) + 1e-5f);
#pragma unroll
      for (int j = 0; j < 4; ++j) qn[j][r] = acc[i][j][r] * inv * wgt[j];
    }
#pragma unroll
    for (int j = 0; j < 4; ++j) {
      int d = j * 16 + l16;
#pragma unroll
      for (int r = 0; r < 4; ++r) {
        int row = row0 + r;
        float rot = (j < 2) ? -qn[j + 2][r] : qn[j - 2][r];   // rotate_half
        float o = qn[j][r] * cosb[row * 64 + d] + rot * sinb[row * 64 + d];
        if (hg < 16)
          qout[(size_t)row * HIDDEN + hg * 64 + d] = f2bf(o * QSCALE);
        else
          kout[((size_t)(hg - 16) * S_LEN + row) * 64 + d] = f2bf(o);
      }
    }
  }
}

// ---------------------------------------------------------------------------
// Kernel 4: C[M][N] = A[M][K] * B[N][K]^T — output projection.
// ---------------------------------------------------------------------------
__global__ __launch_bounds__(256) void k_gemm_bf16(
    const uint16_t* __restrict__ A, const uint16_t* __restrict__ B,
    float* __restrict__ C, int N, int K) {
  __shared__ uint16_t As[64 * 64];
  __shared__ uint16_t Bs[128 * 64];
  const int t = threadIdx.x;
  const int lane = t & 63, w = t >> 6;
  const int wr = w >> 1, wc = w & 1;
  const int l16 = lane & 15, lg = lane >> 4;
  const int bm = blockIdx.x, bn = blockIdx.y;
  const uint16_t* Ab = A + (size_t)bm * 64 * K;
  const uint16_t* Bb = B + (size_t)bn * 128 * K;
  f32x4 acc[2][4] = {};
  for (int k0 = 0; k0 < K; k0 += 64) {
    __syncthreads();
    {
      int row = t >> 3, c8 = (t & 7) << 3;
      gld_lds16(&As[t * 8], Ab + (size_t)row * K + k0 + c8);
      int t2 = t + 256, row2 = t2 >> 3, c82 = (t2 & 7) << 3;
      gld_lds16(&As[t2 * 8], Ab + (size_t)row2 * K + k0 + c82);
    }
#pragma unroll
    for (int it = 0; it < 4; ++it) {
      int idx = it * 256 + t;
      int row = idx >> 3, c8 = (idx & 7) << 3;
      gld_lds16(&Bs[idx * 8], Bb + (size_t)row * K + k0 + c8);
    }
    __syncthreads();
#pragma unroll
    for (int kk = 0; kk < 2; ++kk) {
      short8 af[2], bq[4];
#pragma unroll
      for (int i = 0; i < 2; ++i)
        af[i] = *(const short8*)&As[(wr * 32 + i * 16 + l16) * 64 + kk * 32 + lg * 8];
#pragma unroll
      for (int j = 0; j < 4; ++j)
        bq[j] = *(const short8*)&Bs[(wc * 64 + j * 16 + l16) * 64 + kk * 32 + lg * 8];
#pragma unroll
      for (int i = 0; i < 2; ++i)
#pragma unroll
        for (int j = 0; j < 4; ++j)
          acc[i][j] = __builtin_amdgcn_mfma_f32_16x16x32_bf16(af[i], bq[j], acc[i][j], 0, 0, 0);
    }
  }
#pragma unroll
  for (int i = 0; i < 2; ++i) {
    int row0 = bm * 64 + wr * 32 + i * 16 + lg * 4;
#pragma unroll
    for (int j = 0; j < 4; ++j) {
      int col = bn * 128 + wc * 64 + j * 16 + l16;
#pragma unroll
      for (int r = 0; r < 4; ++r)
        C[(size_t)(row0 + r) * N + col] = acc[i][j][r];
    }
  }
}

// ---------------------------------------------------------------------------
// Kernel 3: sliding-window flash attention — LDS-free, 32x32x16 MFMA.
// Grid (64, 8), 256 threads = 4 waves. Block = 64 q-rows x head-pair (same
// kv group). Wave w: head (w>>1), 32-row q-subtile (w&1).
// Swapped QK^T with 32x32: D[key][q], lane owns q = lane&31 (all 32 keys of a
// subtile in 16 regs). P rebuilt in-register for PV A-operand via pk2 +
// shfl_xor(32) + cndmask (no P-LDS). K/V read directly from global (L1/L2
// resident: 16KB/tile shared by 4 waves). No __syncthreads anywhere.
// Fixed-max softmax: p = exp2(s) (scores bounded by RMSNorm), masks on the 2
// edge tiles only. XCD swizzle: each head-pair pinned to one XCD (1MB K+V in
// its L2); reversed q0 for tail balance.
// ---------------------------------------------------------------------------
__global__ __launch_bounds__(256) void k_attn(
    const uint16_t* __restrict__ qb,   // [S][HIDDEN], pre-scaled by QSCALE
    const uint16_t* __restrict__ kb,   // [KV][S][64]
    const uint16_t* __restrict__ vtb,  // [KV][64][S]
    const float* __restrict__ sinks,
    uint16_t* __restrict__ ao) {       // [S][HIDDEN]
  const int t = threadIdx.x;
  const int lane = t & 63, w = t >> 6;
  const int linear = blockIdx.x + 64 * blockIdx.y;        // 0..511
  const int lid = (linear & 7) * 64 + (linear >> 3);      // bijective XCD swizzle
  const int q0 = (63 - (lid & 63)) * 64;                  // long blocks first
  const int hp = lid >> 6;                                // head-pair 0..7
  const int kvh = hp >> 1;
  const int h = kvh * 4 + (hp & 1) * 2 + (w >> 1);
  const int qbase = q0 + (w & 1) * 32;
  const int l32 = lane & 31, hi = lane >> 5;
  const int qrow = qbase + l32;                           // this lane's q-row

  // Q fragments (B operand): bq[s] = Q[qrow][h*64 + s*16 + hi*8 .. +7]
  short8 bq[4];
  {
    const uint16_t* qp = qb + (size_t)qrow * HIDDEN + h * 64 + hi * 8;
    bq[0] = *(const short8*)(qp);
    bq[1] = *(const short8*)(qp + 16);
    bq[2] = *(const short8*)(qp + 32);
    bq[3] = *(const short8*)(qp + 48);
  }
  const uint16_t* kbase = kb + (size_t)kvh * S_LEN * 64;   // [key][64]
  const uint16_t* vbase = vtb + (size_t)kvh * 64 * S_LEN;  // [d][S]

  f32x16 acc0 = {}, acc1 = {};
  float lsum = 0.f;
  int kstart = q0 - WINDOW;
  if (kstart < 0) kstart = 0;

  for (int k0 = kstart; k0 <= q0; k0 += 64) {
    const bool edge = (k0 == q0) || (k0 == q0 - WINDOW);
    const uint16_t* kt = kbase + (size_t)(k0 + l32) * 64 + hi * 8;
#pragma unroll
    for (int c = 0; c < 2; ++c) {            // two 32-key subtiles
      // S^T = K Q^T: D[key][q], A = K (direct from global, L1-hit)
      f32x16 st = {};
#pragma unroll
      for (int s = 0; s < 4; ++s) {
        short8 ak = *(const short8*)(kt + c * 32 * 64 + s * 16);
        st = __builtin_amdgcn_mfma_f32_32x32x16_bf16(ak, bq[s], st, 0, 0, 0);
      }
      // softmax: p = exp2(st); key = k0 + c*32 + (r&3) + 8*(r>>2) + 4*hi
      float pp[16];
      if (edge) {
#pragma unroll
        for (int r = 0; r < 16; ++r) {
          int key = k0 + c * 32 + 4 * hi + (r & 3) + 8 * (r >> 2);
          bool ok = (key <= qrow) && (key + WINDOW > qrow);
          pp[r] = ok ? exp2f(st[r]) : 0.f;
        }
      } else {
#pragma unroll
        for (int r = 0; r < 16; ++r) pp[r] = exp2f(st[r]);
      }
#pragma unroll
      for (int r = 0; r < 16; ++r) lsum += pp[r];
      // pack to bf16 pairs: wv[i] holds keys {8*(i>>1)+2*(i&1)+4*hi, +1}
      uint32_t wvp[8];
#pragma unroll
      for (int i = 0; i < 8; ++i) wvp[i] = pk2(pp[2 * i], pp[2 * i + 1]);
      // PV: two 16-key steps per subtile; A-frag rebuilt in-register
#pragma unroll
      for (int half = 0; half < 2; ++half) {
        uint32_t x0 = wvp[half * 4 + 0], x1 = wvp[half * 4 + 1];
        uint32_t x2 = wvp[half * 4 + 2], x3 = wvp[half * 4 + 3];
        uint32_t p0 = (uint32_t)__shfl_xor((int)x0, 32);
        uint32_t p1 = (uint32_t)__shfl_xor((int)x1, 32);
        uint32_t p2 = (uint32_t)__shfl_xor((int)x2, 32);
        uint32_t p3 = (uint32_t)__shfl_xor((int)x3, 32);
        // lane l (hi=0): keys 16*half+{0..7} = x0,x1,p0,p1
        // lane l+32 (hi=1): keys 16*half+{8..15} = p2,p3,x2,x3
        uint4 au = { hi ? p2 : x0, hi ? p3 : x1, hi ? x2 : p0, hi ? x3 : p1 };
        short8 pa = __builtin_bit_cast(short8, au);
        const uint16_t* vt = vbase + (size_t)l32 * S_LEN
                           + k0 + c * 32 + half * 16 + hi * 8;
        short8 bv0 = *(const short8*)(vt);
        short8 bv1 = *(const short8*)(vt + 32 * S_LEN);
        acc0 = __builtin_amdgcn_mfma_f32_32x32x16_bf16(pa, bv0, acc0, 0, 0, 0);
        acc1 = __builtin_amdgcn_mfma_f32_32x32x16_bf16(pa, bv1, acc1, 0, 0, 0);
      }
    }
  }

  // denominator: pair (l, l+32) covers all keys of each subtile
  lsum += __shfl_xor(lsum, 32);
  float inv = 1.0f / (lsum + exp2f(sinks[h] * L2E));   // lane holds q = l32
  // acc rows: q-local = (r&3) + 8*(r>>2) + 4*hi; cols: d = dt*32 + l32
#pragma unroll
  for (int r = 0; r < 16; ++r) {
    int rloc = (r & 3) + 8 * (r >> 2) + 4 * hi;
    float rd = __shfl(inv, rloc);                      // inv duplicated in halves
    size_t base = (size_t)(qbase + rloc) * HIDDEN + h * 64 + l32;
    ao[base]      = f2bf(acc0[r] * rd);
    ao[base + 32] = f2bf(acc1[r] * rd);
  }
}

// ---------------------------------------------------------------------------
// Launch. Workspace layout (~33 MB of d_ws):
//   [0,8M)    xb      bf16 x            [4096][1024]
//   [8,11M)   wqkvb   bf16 wq|wk|wv     [1536][1024]
//   [11,13M)  wob     bf16 wo           [1024][1024]
//   [13,21M)  qsc     bf16 q (scaled)   [4096][1024]
//   [21,23M)  kbf     bf16 k            [4][4096][64]
//   [23,25M)  vtb     bf16 v^T          [4][64][4096]
//   [25,33M)  aob     bf16 attn out     [4096][1024]
// ---------------------------------------------------------------------------
extern "C" void kernel_launch(void* const* d_in, const int* in_sizes, int n_in,
                              void* d_out, int out_size, void* d_ws, size_t ws_size,
                              hipStream_t stream) {
  const float* x     = (const float*)d_in[0];
  const float* cosb  = (const float*)d_in[1];
  const float* sinb  = (const float*)d_in[2];
  const float* wq    = (const float*)d_in[3];
  const float* wk    = (const float*)d_in[4];
  const float* wv    = (const float*)d_in[5];
  const float* wo    = (const float*)d_in[6];
  const float* qnw   = (const float*)d_in[7];
  const float* knw   = (const float*)d_in[8];
  const float* sinks = (const float*)d_in[9];
  float* out = (float*)d_out;

  char* ws = (char*)d_ws;
  uint16_t* xb    = (uint16_t*)(ws);
  uint16_t* wqkvb = (uint16_t*)(ws + (8ll  << 20));
  uint16_t* wob   = (uint16_t*)(ws + (11ll << 20));
  uint16_t* qsc   = (uint16_t*)(ws + (13ll << 20));
  uint16_t* kbf   = (uint16_t*)(ws + (21ll << 20));
  uint16_t* vtb   = (uint16_t*)(ws + (23ll << 20));
  uint16_t* aob   = (uint16_t*)(ws + (25ll << 20));

  k_tobf16  <<<6656, 256, 0, stream>>>(x, wq, wk, wv, wo, xb, wqkvb, wob);
  k_gemm_qkv<<<dim3(64, 12), 256, 0, stream>>>(xb, wqkvb, cosb, sinb, qnw, knw,
                                               qsc, kbf, vtb);
  k_attn    <<<dim3(64, 8), 256, 0, stream>>>(qsc, kbf, vtb, sinks, aob);
  k_gemm_bf16<<<dim3(64, 8), 256, 0, stream>>>(aob, wob, out, 1024, 1024);
}

// Round 6
// 81.233 us; speedup vs baseline: 1.1907x; 1.1907x over previous
//
#include <hip/hip_runtime.h>
#include <hip/hip_bf16.h>
#include <stdint.h>

// Problem constants
#define S_LEN   4096
#define HIDDEN  1024
#define NHEAD   16
#define NKV     4
#define HD      64
#define WINDOW  512
#define L2E     1.4426950408889634f
#define QSCALE  (0.125f * L2E)

using short8 = __attribute__((ext_vector_type(8))) short;
using f32x4  = __attribute__((ext_vector_type(4))) float;

// fp32 -> bf16, round-to-nearest-even
__device__ __forceinline__ uint16_t f2bf(float f) {
  uint32_t u = __builtin_bit_cast(uint32_t, f);
  u += 0x7fffu + ((u >> 16) & 1u);
  return (uint16_t)(u >> 16);
}
// round-to-nearest (ties up) — P values only (all >=0, bias ~2^-17)
__device__ __forceinline__ uint16_t f2bf_rn(float f) {
  uint32_t u = __builtin_bit_cast(uint32_t, f);
  return (uint16_t)((u + 0x8000u) >> 16);
}
__device__ __forceinline__ uint32_t pk2(float a, float b) {
  return (uint32_t)f2bf_rn(a) | ((uint32_t)f2bf_rn(b) << 16);
}

// async global->LDS, 16B per lane. LDS dest must be wave-uniform base + lane*16.
__device__ __forceinline__ void gld_lds16(void* lds, const void* g) {
  __builtin_amdgcn_global_load_lds(
      (const __attribute__((address_space(1))) char*)g,
      (__attribute__((address_space(3))) char*)lds, 16, 0, 0);
}

// ---------------------------------------------------------------------------
// Kernel 1: pack x, wq|wk|wv (concat rows), wo to bf16
// ---------------------------------------------------------------------------
__global__ __launch_bounds__(256) void k_tobf16(
    const float* __restrict__ x, const float* __restrict__ wq,
    const float* __restrict__ wk, const float* __restrict__ wv,
    const float* __restrict__ wo,
    uint16_t* __restrict__ xb, uint16_t* __restrict__ wqkvb,
    uint16_t* __restrict__ wob) {
  int i = blockIdx.x * 256 + threadIdx.x;  // one float4 per thread, exact grid
  const float4* src; uint16_t* dst; int off;
  if (i < 1048576)      { src = (const float4*)x;  dst = xb;                off = i; }
  else if (i < 1310720) { src = (const float4*)wq; dst = wqkvb;             off = i - 1048576; }
  else if (i < 1376256) { src = (const float4*)wk; dst = wqkvb + 1024*1024; off = i - 1310720; }
  else if (i < 1441792) { src = (const float4*)wv; dst = wqkvb + 1280*1024; off = i - 1376256; }
  else                  { src = (const float4*)wo; dst = wob;               off = i - 1441792; }
  float4 v = src[off];
  ushort4 o = { f2bf(v.x), f2bf(v.y), f2bf(v.z), f2bf(v.w) };
  *(ushort4*)(dst + (size_t)off * 4) = o;
}

// ---------------------------------------------------------------------------
// Kernel 2: QKV GEMM with fused RMSNorm + RoPE + cast + layout epilogue.
// BM=64, BN=128, BK=64; 4 waves in 2x2, wave tile 32x64 (acc[2][4]).
// Grid (64, 12) = 768 blocks = exactly 3 blocks/CU.
// ---------------------------------------------------------------------------
__global__ __launch_bounds__(256) void k_gemm_qkv(
    const uint16_t* __restrict__ A, const uint16_t* __restrict__ B,
    const float* __restrict__ cosb, const float* __restrict__ sinb,
    const float* __restrict__ qw, const float* __restrict__ kw,
    uint16_t* __restrict__ qout, uint16_t* __restrict__ kout,
    uint16_t* __restrict__ vtout) {
  __shared__ uint16_t As[64 * 64];
  __shared__ uint16_t Bs[128 * 64];
  const int K = 1024;
  const int t = threadIdx.x;
  const int lane = t & 63, w = t >> 6;
  const int wr = w >> 1, wc = w & 1;
  const int l16 = lane & 15, lg = lane >> 4;
  const int bm = blockIdx.x, bn = blockIdx.y;
  const uint16_t* Ab = A + (size_t)bm * 64 * K;
  const uint16_t* Bb = B + (size_t)bn * 128 * K;
  f32x4 acc[2][4] = {};
  for (int k0 = 0; k0 < K; k0 += 64) {
    __syncthreads();
    {  // stage A: 64x64 = 512 16B-chunks -> 2/thread
      int row = t >> 3, c8 = (t & 7) << 3;
      gld_lds16(&As[t * 8], Ab + (size_t)row * K + k0 + c8);
      int t2 = t + 256, row2 = t2 >> 3, c82 = (t2 & 7) << 3;
      gld_lds16(&As[t2 * 8], Ab + (size_t)row2 * K + k0 + c82);
    }
#pragma unroll
    for (int it = 0; it < 4; ++it) {  // stage B: 128x64 -> 4/thread
      int idx = it * 256 + t;
      int row = idx >> 3, c8 = (idx & 7) << 3;
      gld_lds16(&Bs[idx * 8], Bb + (size_t)row * K + k0 + c8);
    }
    __syncthreads();
#pragma unroll
    for (int kk = 0; kk < 2; ++kk) {
      short8 af[2], bq[4];
#pragma unroll
      for (int i = 0; i < 2; ++i)
        af[i] = *(const short8*)&As[(wr * 32 + i * 16 + l16) * 64 + kk * 32 + lg * 8];
#pragma unroll
      for (int j = 0; j < 4; ++j)
        bq[j] = *(const short8*)&Bs[(wc * 64 + j * 16 + l16) * 64 + kk * 32 + lg * 8];
#pragma unroll
      for (int i = 0; i < 2; ++i)
#pragma unroll
        for (int j = 0; j < 4; ++j)
          acc[i][j] = __builtin_amdgcn_mfma_f32_16x16x32_bf16(af[i], bq[j], acc[i][j], 0, 0, 0);
    }
  }

  // ---- fused epilogue ----
  const int hg = bn * 2 + wc;   // global 64-wide head slot, uniform per wave
  if (hg >= 20) {               // V: cast + transposed store
    const int kvh = hg - 20;
#pragma unroll
    for (int i = 0; i < 2; ++i) {
      int row0 = bm * 64 + wr * 32 + i * 16 + lg * 4;
#pragma unroll
      for (int j = 0; j < 4; ++j) {
        int d = j * 16 + l16;
        ushort4 o = { f2bf(acc[i][j][0]), f2bf(acc[i][j][1]),
                      f2bf(acc[i][j][2]), f2bf(acc[i][j][3]) };
        *(ushort4*)(vtout + (size_t)(kvh * 64 + d) * S_LEN + row0) = o;
      }
    }
    return;
  }
  // Q/K: RMSNorm + RoPE
  const float* nw = (hg < 16) ? qw : kw;
  float wgt[4];
#pragma unroll
  for (int j = 0; j < 4; ++j) wgt[j] = nw[j * 16 + l16];
#pragma unroll
  for (int i = 0; i < 2; ++i) {
    int row0 = bm * 64 + wr * 32 + i * 16 + lg * 4;
    float qn[4][4];
#pragma unroll
    for (int r = 0; r < 4; ++r) {
      float ss = acc[i][0][r] * acc[i][0][r] + acc[i][1][r] * acc[i][1][r]
               + acc[i][2][r] * acc[i][2][r] + acc[i][3][r] * acc[i][3][r];
      ss += __shfl_xor(ss, 1);
      ss += __shfl_xor(ss, 2);
      ss += __shfl_xor(ss, 4);
      ss += __shfl_xor(ss, 8);
      float inv = rsqrtf(ss * (1.0f / 64.0f) + 1e-5f);
#pragma unroll
      for (int j = 0; j < 4; ++j) qn[j][r] = acc[i][j][r] * inv * wgt[j];
    }
#pragma unroll
    for (int j = 0; j < 4; ++j) {
      int d = j * 16 + l16;
#pragma unroll
      for (int r = 0; r < 4; ++r) {
        int row = row0 + r;
        float rot = (j < 2) ? -qn[j + 2][r] : qn[j - 2][r];   // rotate_half
        float o = qn[j][r] * cosb[row * 64 + d] + rot * sinb[row * 64 + d];
        if (hg < 16)
          qout[(size_t)row * HIDDEN + hg * 64 + d] = f2bf(o * QSCALE);
        else
          kout[((size_t)(hg - 16) * S_LEN + row) * 64 + d] = f2bf(o);
      }
    }
  }
}

// ---------------------------------------------------------------------------
// Kernel 4: C[M][N] = A[M][K] * B[N][K]^T — output projection.
// ---------------------------------------------------------------------------
__global__ __launch_bounds__(256) void k_gemm_bf16(
    const uint16_t* __restrict__ A, const uint16_t* __restrict__ B,
    float* __restrict__ C, int N, int K) {
  __shared__ uint16_t As[64 * 64];
  __shared__ uint16_t Bs[128 * 64];
  const int t = threadIdx.x;
  const int lane = t & 63, w = t >> 6;
  const int wr = w >> 1, wc = w & 1;
  const int l16 = lane & 15, lg = lane >> 4;
  const int bm = blockIdx.x, bn = blockIdx.y;
  const uint16_t* Ab = A + (size_t)bm * 64 * K;
  const uint16_t* Bb = B + (size_t)bn * 128 * K;
  f32x4 acc[2][4] = {};
  for (int k0 = 0; k0 < K; k0 += 64) {
    __syncthreads();
    {
      int row = t >> 3, c8 = (t & 7) << 3;
      gld_lds16(&As[t * 8], Ab + (size_t)row * K + k0 + c8);
      int t2 = t + 256, row2 = t2 >> 3, c82 = (t2 & 7) << 3;
      gld_lds16(&As[t2 * 8], Ab + (size_t)row2 * K + k0 + c82);
    }
#pragma unroll
    for (int it = 0; it < 4; ++it) {
      int idx = it * 256 + t;
      int row = idx >> 3, c8 = (idx & 7) << 3;
      gld_lds16(&Bs[idx * 8], Bb + (size_t)row * K + k0 + c8);
    }
    __syncthreads();
#pragma unroll
    for (int kk = 0; kk < 2; ++kk) {
      short8 af[2], bq[4];
#pragma unroll
      for (int i = 0; i < 2; ++i)
        af[i] = *(const short8*)&As[(wr * 32 + i * 16 + l16) * 64 + kk * 32 + lg * 8];
#pragma unroll
      for (int j = 0; j < 4; ++j)
        bq[j] = *(const short8*)&Bs[(wc * 64 + j * 16 + l16) * 64 + kk * 32 + lg * 8];
#pragma unroll
      for (int i = 0; i < 2; ++i)
#pragma unroll
        for (int j = 0; j < 4; ++j)
          acc[i][j] = __builtin_amdgcn_mfma_f32_16x16x32_bf16(af[i], bq[j], acc[i][j], 0, 0, 0);
    }
  }
#pragma unroll
  for (int i = 0; i < 2; ++i) {
    int row0 = bm * 64 + wr * 32 + i * 16 + lg * 4;
#pragma unroll
    for (int j = 0; j < 4; ++j) {
      int col = bn * 128 + wc * 64 + j * 16 + l16;
#pragma unroll
      for (int r = 0; r < 4; ++r)
        C[(size_t)(row0 + r) * N + col] = acc[i][j][r];
    }
  }
}

// ---------------------------------------------------------------------------
// Kernel 3: sliding-window flash attention, SWAPPED QK^T (round-4 structure)
// + T14 async-STAGE split + T5 setprio.
// Grid (S/64, 8), 512 threads = 8 waves. Block = one 64-row q-tile x two
// heads of one kv group. Wave w: head (w>>2), q-subtile (w&3).
// T14: next tile's K/V global loads issued into regs right after the compute
// barrier (fly under QK/softmax/PV); committed to LDS after the next barrier.
// Fixed-max softmax (scores bounded by RMSNorm): p = exp2(s), no online max.
// ---------------------------------------------------------------------------
__global__ __launch_bounds__(512) void k_attn(
    const uint16_t* __restrict__ qb,   // [S][HIDDEN], pre-scaled by QSCALE
    const uint16_t* __restrict__ kb,   // [KV][S][64]
    const uint16_t* __restrict__ vtb,  // [KV][64][S]
    const float* __restrict__ sinks,
    uint16_t* __restrict__ ao) {       // [S][HIDDEN]
  __shared__ uint16_t Kl[64][72];      // +8 pad
  __shared__ uint16_t Vl[64][72];      // V^T tile: [d][key]
  __shared__ uint16_t Pl[8][16][72];   // per-wave P: [q(16)][key(64)+pad]
  const int q0 = (63 - blockIdx.x) * 64;   // long blocks first
  const int hp = blockIdx.y;               // head-pair 0..7
  const int kvh = hp >> 1;
  const int t = threadIdx.x;
  const int lane = t & 63, w = t >> 6;
  const int h = kvh * 4 + (hp & 1) * 2 + (w >> 2);
  const int wq = w & 3;
  const int l16 = lane & 15, lg = lane >> 4;
  const int qrow = q0 + wq * 16 + l16;     // this lane's q-row

  // Q fragment, used as the B operand (n = l16 = q-row)
  short8 bq0, bq1;
  {
    const uint16_t* qp = qb + (size_t)qrow * HIDDEN + h * 64 + lg * 8;
    bq0 = *(const short8*)qp;
    bq1 = *(const short8*)(qp + 32);
  }
  float lsum = 0.f;
  f32x4 acc[4] = {};

  int kstart = q0 - WINDOW;
  if (kstart < 0) kstart = 0;

  // staging: thread t owns (row = t>>3, 16B chunk = t&7) of both tiles
  const int srow = t >> 3, sc8 = (t & 7) << 3;
  const uint16_t* kp = kb + ((size_t)kvh * S_LEN + srow) * 64 + sc8;
  const uint16_t* vp = vtb + ((size_t)kvh * 64 + srow) * S_LEN + sc8;
  // prologue: first tile into regs
  short8 nk = *(const short8*)(kp + (size_t)kstart * 64);
  short8 nv = *(const short8*)(vp + kstart);

  for (int k0 = kstart; k0 <= q0; k0 += 64) {
    __syncthreads();                   // previous tile fully consumed
    *(short8*)&Kl[srow][sc8] = nk;     // commit prefetched tile (vmcnt wait here)
    *(short8*)&Vl[srow][sc8] = nv;
    __syncthreads();
    if (k0 + 64 <= q0) {               // T14: issue next-tile loads NOW
      nk = *(const short8*)(kp + (size_t)(k0 + 64) * 64);
      nv = *(const short8*)(vp + k0 + 64);
    }

    // S^T = K Q^T: D[m=key][n=q]
    f32x4 st[4] = {};
    __builtin_amdgcn_s_setprio(1);
#pragma unroll
    for (int c = 0; c < 4; ++c) {
      short8 ak0 = *(const short8*)&Kl[c * 16 + l16][lg * 8];
      short8 ak1 = *(const short8*)&Kl[c * 16 + l16][32 + lg * 8];
      st[c] = __builtin_amdgcn_mfma_f32_16x16x32_bf16(ak0, bq0, st[c], 0, 0, 0);
      st[c] = __builtin_amdgcn_mfma_f32_16x16x32_bf16(ak1, bq1, st[c], 0, 0, 0);
    }
    __builtin_amdgcn_s_setprio(0);

    // key = k0 + c*16 + lg*4 + r; q-row = qrow (lane-local). Mask edge tiles.
    float p[4][4];
    if (k0 == q0 || k0 == q0 - WINDOW) {
#pragma unroll
      for (int c = 0; c < 4; ++c) {
        int keyb = k0 + c * 16 + lg * 4;
#pragma unroll
        for (int r = 0; r < 4; ++r) {
          int key = keyb + r;
          bool ok = (key <= qrow) && (key + WINDOW > qrow);
          p[c][r] = ok ? exp2f(st[c][r]) : 0.f;
        }
      }
    } else {
#pragma unroll
      for (int c = 0; c < 4; ++c)
#pragma unroll
        for (int r = 0; r < 4; ++r)
          p[c][r] = exp2f(st[c][r]);
    }
#pragma unroll
    for (int c = 0; c < 4; ++c)
      lsum += (p[c][0] + p[c][1]) + (p[c][2] + p[c][3]);

    // pack P (keys consecutive in r) -> [q][key] LDS layout, 8B stores
#pragma unroll
    for (int c = 0; c < 4; ++c) {
      uint2 pw = { pk2(p[c][0], p[c][1]), pk2(p[c][2], p[c][3]) };
      *(uint2*)&Pl[w][l16][c * 16 + lg * 4] = pw;
    }
    asm volatile("s_waitcnt lgkmcnt(0)" ::: "memory");
    short8 pa0 = *(const short8*)&Pl[w][l16][lg * 8];
    short8 pa1 = *(const short8*)&Pl[w][l16][32 + lg * 8];
    __builtin_amdgcn_s_setprio(1);
#pragma unroll
    for (int dt = 0; dt < 4; ++dt) {
      short8 bv0 = *(const short8*)&Vl[dt * 16 + l16][lg * 8];
      short8 bv1 = *(const short8*)&Vl[dt * 16 + l16][32 + lg * 8];
      acc[dt] = __builtin_amdgcn_mfma_f32_16x16x32_bf16(pa0, bv0, acc[dt], 0, 0, 0);
      acc[dt] = __builtin_amdgcn_mfma_f32_16x16x32_bf16(pa1, bv1, acc[dt], 0, 0, 0);
    }
    __builtin_amdgcn_s_setprio(0);
  }

  // lsum: reduce across the 4 lg-groups (lanes sharing l16), add sink
  lsum += __shfl_xor(lsum, 16);
  lsum += __shfl_xor(lsum, 32);
  float sk = exp2f(sinks[h] * L2E);
  float inv = 1.0f / (lsum + sk);     // lane (l16,lg) holds inv for local row l16
  // acc rows are local row lg*4+r -> fetch inv from lane (lg*4+r)
#pragma unroll
  for (int r = 0; r < 4; ++r) {
    float rd = __shfl(inv, lg * 4 + r);
    int row = q0 + wq * 16 + lg * 4 + r;
#pragma unroll
    for (int dt = 0; dt < 4; ++dt)
      ao[(size_t)row * HIDDEN + h * 64 + dt * 16 + l16] = f2bf(acc[dt][r] * rd);
  }
}

// ---------------------------------------------------------------------------
// Launch. Workspace layout (~33 MB of d_ws):
//   [0,8M)    xb      bf16 x            [4096][1024]
//   [8,11M)   wqkvb   bf16 wq|wk|wv     [1536][1024]
//   [11,13M)  wob     bf16 wo           [1024][1024]
//   [13,21M)  qsc     bf16 q (scaled)   [4096][1024]
//   [21,23M)  kbf     bf16 k            [4][4096][64]
//   [23,25M)  vtb     bf16 v^T          [4][64][4096]
//   [25,33M)  aob     bf16 attn out     [4096][1024]
// ---------------------------------------------------------------------------
extern "C" void kernel_launch(void* const* d_in, const int* in_sizes, int n_in,
                              void* d_out, int out_size, void* d_ws, size_t ws_size,
                              hipStream_t stream) {
  const float* x     = (const float*)d_in[0];
  const float* cosb  = (const float*)d_in[1];
  const float* sinb  = (const float*)d_in[2];
  const float* wq    = (const float*)d_in[3];
  const float* wk    = (const float*)d_in[4];
  const float* wv    = (const float*)d_in[5];
  const float* wo    = (const float*)d_in[6];
  const float* qnw   = (const float*)d_in[7];
  const float* knw   = (const float*)d_in[8];
  const float* sinks = (const float*)d_in[9];
  float* out = (float*)d_out;

  char* ws = (char*)d_ws;
  uint16_t* xb    = (uint16_t*)(ws);
  uint16_t* wqkvb = (uint16_t*)(ws + (8ll  << 20));
  uint16_t* wob   = (uint16_t*)(ws + (11ll << 20));
  uint16_t* qsc   = (uint16_t*)(ws + (13ll << 20));
  uint16_t* kbf   = (uint16_t*)(ws + (21ll << 20));
  uint16_t* vtb   = (uint16_t*)(ws + (23ll << 20));
  uint16_t* aob   = (uint16_t*)(ws + (25ll << 20));

  k_tobf16  <<<6656, 256, 0, stream>>>(x, wq, wk, wv, wo, xb, wqkvb, wob);
  k_gemm_qkv<<<dim3(64, 12), 256, 0, stream>>>(xb, wqkvb, cosb, sinb, qnw, knw,
                                               qsc, kbf, vtb);
  k_attn    <<<dim3(64, 8), 512, 0, stream>>>(qsc, kbf, vtb, sinks, aob);
  k_gemm_bf16<<<dim3(64, 8), 256, 0, stream>>>(aob, wob, out, 1024, 1024);
}